// Round 4
// baseline (107.837 us; speedup 1.0000x reference)
//
#include <hip/hip_runtime.h>
#include <math.h>
#include <stdint.h>

#define NLAT 128
#define NLON 256
#define LMAX 50
#define MMAX 50
#define MGRID (NLAT*NLON)   // 32768
#define BATCH 2
#define NPTS 2048
#define PI_F 3.14159265358979323846f

typedef float v2f __attribute__((ext_vector_type(2)));

__device__ __forceinline__ uint32_t umin32(uint32_t a, uint32_t b) { return a < b ? a : b; }
__device__ __forceinline__ uint32_t umax32(uint32_t a, uint32_t b) { return a > b ? a : b; }
// forced v_med3_u32 (median of 3) — top-3 insert: k1' = med3(x, k0, k1)
__device__ __forceinline__ uint32_t med3u(uint32_t a, uint32_t b, uint32_t c) {
    uint32_t d;
    asm("v_med3_u32 %0, %1, %2, %3" : "=v"(d) : "v"(a), "v"(b), "v"(c));
    return d;
}

// ============ kernel 1: inline cart->sph + 3-NN + weighted combine -> f
// 1024 blocks (512 grid-tiles x 2 batches), 4 waves/block; each wave = same
// 64 grid points, disjoint 512-candidate partition; LDS merge of top-3 keys.
__global__ __launch_bounds__(256, 4)
void k_nn(const float* __restrict__ target, float* __restrict__ f) {
    __shared__ float2   s_pt[NPTS];
    __shared__ float    s_rho[NPTS];
    __shared__ uint32_t s_keys[4][64][3];
    int b     = blockIdx.x >> 9;
    int gtile = blockIdx.x & 511;
    const float* tg = target + b * NPTS * 3;
    // cart -> spherical for all 2048 points of this batch (redundant per block,
    // ~0.3us; removes the separate prep kernel + sph/rho ws round-trip)
    for (int p = threadIdx.x; p < NPTS; p += 256) {
        float x = tg[p*3+0], y = tg[p*3+1], z = tg[p*3+2];
        float r = sqrtf(fmaf(x, x, fmaf(y, y, z*z)));
        float phi = atan2f(y, x);
        float c = fminf(1.0f, fmaxf(-1.0f, z / r));
        s_pt[p]  = make_float2(phi, acosf(c) - PI_F);
        s_rho[p] = r;
    }
    __syncthreads();
    int lane = threadIdx.x & 63;
    int wv   = threadIdx.x >> 6;
    int gp   = gtile * 64 + lane;                       // 0..32767
    float gx = (float)(gp >> 8) * (PI_F / 128.0f);
    float gy = (float)((gp & 255) - 128) * (PI_F / 128.0f);
    v2f gx2 = {gx, gx}, gy2 = {gy, gy};
    uint32_t k0 = 0xFFFFFFFFu, k1 = 0xFFFFFFFFu, k2 = 0xFFFFFFFFu;
    uint32_t nbase = (uint32_t)(wv * 512);
    const float4* pt4 = (const float4*)(s_pt + wv * 512);
    #pragma unroll 8
    for (int j = 0; j < 256; ++j) {                     // 2 candidates / iter
        float4 q = pt4[j];                              // wave-uniform b128
        v2f px = {q.x, q.z}, py = {q.y, q.w};
        v2f dp = gx2 - px;
        v2f dt = gy2 - py;
        v2f d  = dp * dp;
        d = dt * dt + d;                                // v_pk_fma_f32
        uint32_t key0 = (__float_as_uint(d.x) & 0xFFFFF800u) | (nbase + 2u*j);
        uint32_t t0 = umin32(key0, k0);
        uint32_t t1 = med3u(key0, k0, k1);
        k2 = umin32(umax32(key0, k1), k2);
        k0 = t0; k1 = t1;
        uint32_t key1 = (__float_as_uint(d.y) & 0xFFFFF800u) | (nbase + 2u*j + 1u);
        t0 = umin32(key1, k0);
        t1 = med3u(key1, k0, k1);
        k2 = umin32(umax32(key1, k1), k2);
        k0 = t0; k1 = t1;
    }
    s_keys[wv][lane][0] = k0;
    s_keys[wv][lane][1] = k1;
    s_keys[wv][lane][2] = k2;
    __syncthreads();
    if (threadIdx.x < 64) {
        uint32_t m0 = 0xFFFFFFFFu, m1 = 0xFFFFFFFFu, m2 = 0xFFFFFFFFu;
        #pragma unroll
        for (int w = 0; w < 4; ++w) {
            #pragma unroll
            for (int s = 0; s < 3; ++s) {
                uint32_t key = s_keys[w][threadIdx.x][s];
                uint32_t t0 = umin32(key, m0);
                uint32_t t1 = med3u(key, m0, m1);
                m2 = umin32(umax32(key, m1), m2);
                m0 = t0; m1 = t1;
            }
        }
        int i0 = m0 & 2047, i1 = m1 & 2047, i2 = m2 & 2047;
        float2 p0 = s_pt[i0], p1 = s_pt[i1], p2 = s_pt[i2];
        float e, r0, r1, r2;
        e = gx - p0.x; r0 = e*e; e = gy - p0.y; r0 = sqrtf(fmaf(e, e, r0));
        e = gx - p1.x; r1 = e*e; e = gy - p1.y; r1 = sqrtf(fmaf(e, e, r1));
        e = gx - p2.x; r2 = e*e; e = gy - p2.y; r2 = sqrtf(fmaf(e, e, r2));
        float sum = r0 + r1 + r2;
        float interp = (s_rho[i0]*r0 + s_rho[i1]*r1 + s_rho[i2]*r2) / sum;
        f[b * MGRID + gp] = interp;
    }
}

// ============ kernel 2: fused W-gen + truncated-DFT (lon) + Legendre
// contraction (lat). One block per (b,m). W[m][l][k]*cc_w generated into LDS
// (no prep kernel, no W global traffic); f[b] staged in 16-row chunks with
// coalesced float4 loads; rows pitch 257 -> conflict-free DFT reads.
__global__ __launch_bounds__(256)
void k_fftsht(const float* __restrict__ f, float* __restrict__ out) {
    __shared__ float rows[16*257];      // 16.4 KB
    __shared__ float red[16*17];        // 1.1 KB (also reused for contraction)
    __shared__ float sFre[NLAT];        // 0.5 KB
    __shared__ float Wl[LMAX*129];      // 25.8 KB, pitch 129 breaks bank aliasing
    int b = blockIdx.x / MMAX;
    int m = blockIdx.x % MMAX;
    int tid = threadIdx.x;

    // ---- phase A: W[m][l][k] * cc_weight(k) into Wl[l*129+k]
    if (tid < NLAT) {
        int k = tid;
        float theta = (PI_F * (float)k) / 127.0f;
        float x = __cosf(theta), s = __sinf(theta);
        float S = 0.0f;
        for (int kk = 1; kk <= 63; ++kk)
            S += 2.0f / (4.0f*kk*kk - 1.0f) * __cosf(2.0f * theta * (float)kk);
        float w = (2.0f/127.0f) * (1.0f - S);
        if (k == 0 || k == NLAT-1) w *= 0.5f;
        float pmm = sqrtf(1.0f / (4.0f * PI_F));
        for (int i = 1; i <= m; ++i)
            pmm = -sqrtf((2.0f*i + 1.0f) / (2.0f*i)) * s * pmm;
        for (int l = 0; l < m; ++l) Wl[l*129 + k] = 0.0f;
        float Plm2 = pmm;
        Wl[m*129 + k] = Plm2 * w;
        if (m + 1 < LMAX) {
            float Plm1 = sqrtf(2.0f*m + 3.0f) * x * pmm;
            Wl[(m+1)*129 + k] = Plm1 * w;
            for (int l = m + 2; l < LMAX; ++l) {
                float fl = (float)l, fm2 = (float)(m*m);
                float a  = sqrtf((4.0f*fl*fl - 1.0f) / (fl*fl - fm2));
                float bb = sqrtf(((fl-1.0f)*(fl-1.0f) - fm2) /
                                 (4.0f*(fl-1.0f)*(fl-1.0f) - 1.0f));
                float P = a * (x * Plm1 - bb * Plm2);
                Wl[l*129 + k] = P * w;
                Plm2 = Plm1; Plm1 = P;
            }
        }
    }

    // ---- phase B: DFT over lon, 8 chunks of 16 rows
    int kl = tid >> 4, jg = tid & 15;
    const float4* fb4 = (const float4*)(f + b * MGRID);
    for (int c = 0; c < 8; ++c) {
        __syncthreads();                              // rows free to overwrite
        #pragma unroll
        for (int i = 0; i < 4; ++i) {
            int fi4 = c*1024 + tid + i*256;           // float4 index, coalesced
            float4 v = fb4[fi4];
            int fi = fi4 * 4;
            int kk = (fi >> 8) & 15;
            int jj = fi & 255;
            rows[kk*257 + jj + 0] = v.x;
            rows[kk*257 + jj + 1] = v.y;
            rows[kk*257 + jj + 2] = v.z;
            rows[kk*257 + jj + 3] = v.w;
        }
        __syncthreads();
        float acc = 0.0f;
        int jbase = jg * 16;
        int a = (m * jbase) & 255;
        #pragma unroll
        for (int j = 0; j < 16; ++j) {                // conflict-free reads
            acc = fmaf(rows[kl*257 + jbase + j],
                       __cosf((float)a * (2.0f * PI_F / 256.0f)), acc);
            a = (a + m) & 255;
        }
        red[kl*17 + jg] = acc;
        __syncthreads();
        if (tid < 16) {
            float ssum = 0.0f;
            #pragma unroll
            for (int g = 0; g < 16; ++g) ssum += red[tid*17 + g];
            sFre[c*16 + tid] = ssum * (2.0f * PI_F / 256.0f);
        }
    }
    __syncthreads();

    // ---- phase C: out[b,l,m] = sum_k Wl[l][k] * sFre[k]
    float acc = 0.0f;
    if (tid < 200) {
        int l = tid >> 2, kq = tid & 3;
        #pragma unroll 8
        for (int i = 0; i < 32; ++i)
            acc = fmaf(Wl[l*129 + kq*32 + i], sFre[kq*32 + i], acc);
    }
    __syncthreads();                                  // red reads of chunk 7 done
    red[tid < 200 ? tid : 200] = acc;                 // harmless dummy slot (red has 272)
    __syncthreads();
    if (tid < LMAX)
        out[(b*LMAX + tid)*MMAX + m] =
            red[4*tid] + red[4*tid+1] + red[4*tid+2] + red[4*tid+3];
}

extern "C" void kernel_launch(void* const* d_in, const int* in_sizes, int n_in,
                              void* d_out, int out_size, void* d_ws, size_t ws_size,
                              hipStream_t stream) {
    const float* target = (const float*)d_in[0];
    float* out = (float*)d_out;
    float* f   = (float*)d_ws;                        // B*MGRID = 65536 floats

    k_nn<<<1024, 256, 0, stream>>>(target, f);
    k_fftsht<<<BATCH*MMAX, 256, 0, stream>>>(f, out);
}

// Round 5
// 94.662 us; speedup vs baseline: 1.1392x; 1.1392x over previous
//
#include <hip/hip_runtime.h>
#include <math.h>
#include <stdint.h>

#define NLAT 128
#define NLON 256
#define LMAX 50
#define MMAX 50
#define MGRID (NLAT*NLON)   // 32768
#define BATCH 2
#define NPTS 2048
#define NBKT 64
#define PI_F 3.14159265358979323846f

typedef float v2f __attribute__((ext_vector_type(2)));

__device__ __forceinline__ uint32_t umin32(uint32_t a, uint32_t b) { return a < b ? a : b; }
__device__ __forceinline__ uint32_t umax32(uint32_t a, uint32_t b) { return a > b ? a : b; }

// ============ kernel 0: cart->sph + counting-sort by theta bucket ============
// grid = 2 blocks (one per batch), 256 threads. Outputs theta-sorted
// (phi,py) pairs + rho + 65-entry bucket prefix per batch.
__global__ __launch_bounds__(256)
void k_sort(const float* __restrict__ target,
            float2* __restrict__ pt_s, float* __restrict__ rho_s,
            int* __restrict__ bstart) {
    __shared__ float sph_ph[NPTS], sph_py[NPTS], sph_rh[NPTS];
    __shared__ int cnt[NBKT], start[NBKT + 1], cur[NBKT];
    int b = blockIdx.x;
    const float* tg = target + b * NPTS * 3;
    if (threadIdx.x < NBKT) cnt[threadIdx.x] = 0;
    __syncthreads();
    for (int p = threadIdx.x; p < NPTS; p += 256) {
        float x = tg[p*3], y = tg[p*3+1], z = tg[p*3+2];
        float r = sqrtf(fmaf(x, x, fmaf(y, y, z*z)));
        float phi = atan2f(y, x);
        float c = fminf(1.f, fmaxf(-1.f, z / r));
        float py = acosf(c) - PI_F;                    // [-pi, 0]
        sph_ph[p] = phi; sph_py[p] = py; sph_rh[p] = r;
        int bk = (int)floorf((py + PI_F) * ((float)NBKT / PI_F));
        bk = min(NBKT-1, max(0, bk));
        atomicAdd(&cnt[bk], 1);
    }
    __syncthreads();
    if (threadIdx.x == 0) {
        int s = 0;
        for (int i = 0; i < NBKT; ++i) { start[i] = s; cur[i] = s; s += cnt[i]; }
        start[NBKT] = s;
    }
    __syncthreads();
    if (threadIdx.x <= NBKT) bstart[b*(NBKT+1) + threadIdx.x] = start[threadIdx.x];
    for (int p = threadIdx.x; p < NPTS; p += 256) {
        float py = sph_py[p];
        int bk = (int)floorf((py + PI_F) * ((float)NBKT / PI_F));
        bk = min(NBKT-1, max(0, bk));
        int pos = atomicAdd(&cur[bk], 1);
        pt_s[b*NPTS + pos]  = make_float2(sph_ph[p], py);
        rho_s[b*NPTS + pos] = sph_rh[p];
    }
}

// ============ kernel 1: windowed 3-NN + weighted combine -> f ============
// One block per (b, lon j): gy uniform per block. 8 waves: waves 0-3 = lats
// 0..63 x candidate partitions 0-3; waves 4-7 = lats 64..127 x partitions.
// Candidate window: theta-sorted buckets [c-8, c+8], expanded to >=256 cands.
__global__ __launch_bounds__(512, 2)
void k_nn(const float2* __restrict__ pt_s, const float* __restrict__ rho_s,
          const int* __restrict__ bstart, float* __restrict__ f) {
    __shared__ __attribute__((aligned(16))) float2 s_pt[2056];
    __shared__ float    s_rho[2056];
    __shared__ uint32_t s_keys[8][64][3];
    int b = blockIdx.x >> 8;
    int j = blockIdx.x & 255;
    float gy = (float)(j - 128) * (PI_F / 128.0f);
    const int* bs = bstart + b * (NBKT + 1);
    int c = (int)floorf((gy + PI_F) * ((float)NBKT / PI_F));
    c = min(NBKT-1, max(0, c));
    int lo = max(0, c - 8), hi = min(NBKT-1, c + 8);
    int cnt = bs[hi+1] - bs[lo];
    while (cnt < 256 && (lo > 0 || hi < NBKT-1)) {   // block-uniform expansion
        if (lo > 0) --lo;
        if (hi < NBKT-1) ++hi;
        cnt = bs[hi+1] - bs[lo];
    }
    int off = bs[lo];
    for (int i = threadIdx.x; i < cnt; i += 512) {
        s_pt[i]  = pt_s[b*NPTS + off + i];
        s_rho[i] = rho_s[b*NPTS + off + i];
    }
    int q = ((cnt + 3) / 4 + 1) & ~1;                // even partition len, 4q>=cnt, <=2052
    for (int i = cnt + threadIdx.x; i < 4*q; i += 512) {
        s_pt[i] = make_float2(1e15f, 1e15f);         // sentinel: never wins
        s_rho[i] = 0.f;
    }
    __syncthreads();

    int lane = threadIdx.x & 63;
    int wv   = threadIdx.x >> 6;                     // 0..7
    int part = wv & 3;
    int lat  = lane + ((wv >> 2) << 6);
    float gx = (float)lat * (PI_F / 128.0f);
    v2f gx2 = {gx, gx}, gy2 = {gy, gy};
    uint32_t k0 = ~0u, k1 = ~0u, k2 = ~0u;
    uint32_t nb = (uint32_t)(part * q);
    const float4* p4 = (const float4*)(s_pt + part * q);
    int iters = q >> 1;
    #pragma unroll 4
    for (int i = 0; i < iters; ++i) {
        float4 Q = p4[i];                            // wave-uniform b128 broadcast
        v2f px = {Q.x, Q.z}, py = {Q.y, Q.w};
        v2f dp = gx2 - px, dt = gy2 - py;
        v2f d = dp * dp;
        d = dt * dt + d;                             // packed fma
        uint32_t key0 = (__float_as_uint(d.x) & 0xFFFFF800u) | (nb + 2u*i);
        uint32_t key1 = (__float_as_uint(d.y) & 0xFFFFF800u) | (nb + 2u*i + 1u);
        uint32_t t1;
        t1 = umin32(umax32(key0, k0), k1);           // med3 pattern
        k2 = umin32(umax32(key0, k1), k2);
        k0 = umin32(key0, k0); k1 = t1;
        t1 = umin32(umax32(key1, k0), k1);
        k2 = umin32(umax32(key1, k1), k2);
        k0 = umin32(key1, k0); k1 = t1;
    }
    s_keys[wv][lane][0] = k0;
    s_keys[wv][lane][1] = k1;
    s_keys[wv][lane][2] = k2;
    __syncthreads();

    if (threadIdx.x < 128) {
        int lane2 = threadIdx.x & 63;
        int half  = threadIdx.x >> 6;
        uint32_t m0 = ~0u, m1 = ~0u, m2 = ~0u;
        #pragma unroll
        for (int w = half*4; w < half*4 + 4; ++w) {
            #pragma unroll
            for (int s = 0; s < 3; ++s) {
                uint32_t key = s_keys[w][lane2][s];
                uint32_t t1 = umin32(umax32(key, m0), m1);
                m2 = umin32(umax32(key, m1), m2);
                m0 = umin32(key, m0); m1 = t1;
            }
        }
        int i0 = m0 & 2047, i1 = m1 & 2047, i2 = m2 & 2047;
        int lat2 = lane2 + (half << 6);
        float gx2s = (float)lat2 * (PI_F / 128.0f);
        float2 p0 = s_pt[i0], p1 = s_pt[i1], p2 = s_pt[i2];
        float e, r0, r1, r2;
        e = gx2s - p0.x; r0 = e*e; e = gy - p0.y; r0 = sqrtf(fmaf(e, e, r0));
        e = gx2s - p1.x; r1 = e*e; e = gy - p1.y; r1 = sqrtf(fmaf(e, e, r1));
        e = gx2s - p2.x; r2 = e*e; e = gy - p2.y; r2 = sqrtf(fmaf(e, e, r2));
        float sum = r0 + r1 + r2;
        float interp = (s_rho[i0]*r0 + s_rho[i1]*r1 + s_rho[i2]*r2) / sum;
        f[b * MGRID + lat2 * NLON + j] = interp;
    }
}

// ============ kernel 2: fused W-gen + truncated-DFT + Legendre contraction
// (unchanged from round 4 — verified correct)
__global__ __launch_bounds__(256)
void k_fftsht(const float* __restrict__ f, float* __restrict__ out) {
    __shared__ float rows[16*257];
    __shared__ float red[16*17];
    __shared__ float sFre[NLAT];
    __shared__ float Wl[LMAX*129];
    int b = blockIdx.x / MMAX;
    int m = blockIdx.x % MMAX;
    int tid = threadIdx.x;

    if (tid < NLAT) {
        int k = tid;
        float theta = (PI_F * (float)k) / 127.0f;
        float x = __cosf(theta), s = __sinf(theta);
        float S = 0.0f;
        for (int kk = 1; kk <= 63; ++kk)
            S += 2.0f / (4.0f*kk*kk - 1.0f) * __cosf(2.0f * theta * (float)kk);
        float w = (2.0f/127.0f) * (1.0f - S);
        if (k == 0 || k == NLAT-1) w *= 0.5f;
        float pmm = sqrtf(1.0f / (4.0f * PI_F));
        for (int i = 1; i <= m; ++i)
            pmm = -sqrtf((2.0f*i + 1.0f) / (2.0f*i)) * s * pmm;
        for (int l = 0; l < m; ++l) Wl[l*129 + k] = 0.0f;
        float Plm2 = pmm;
        Wl[m*129 + k] = Plm2 * w;
        if (m + 1 < LMAX) {
            float Plm1 = sqrtf(2.0f*m + 3.0f) * x * pmm;
            Wl[(m+1)*129 + k] = Plm1 * w;
            for (int l = m + 2; l < LMAX; ++l) {
                float fl = (float)l, fm2 = (float)(m*m);
                float a  = sqrtf((4.0f*fl*fl - 1.0f) / (fl*fl - fm2));
                float bb = sqrtf(((fl-1.0f)*(fl-1.0f) - fm2) /
                                 (4.0f*(fl-1.0f)*(fl-1.0f) - 1.0f));
                float P = a * (x * Plm1 - bb * Plm2);
                Wl[l*129 + k] = P * w;
                Plm2 = Plm1; Plm1 = P;
            }
        }
    }

    int kl = tid >> 4, jg = tid & 15;
    const float4* fb4 = (const float4*)(f + b * MGRID);
    for (int c = 0; c < 8; ++c) {
        __syncthreads();
        #pragma unroll
        for (int i = 0; i < 4; ++i) {
            int fi4 = c*1024 + tid + i*256;
            float4 v = fb4[fi4];
            int fi = fi4 * 4;
            int kk = (fi >> 8) & 15;
            int jj = fi & 255;
            rows[kk*257 + jj + 0] = v.x;
            rows[kk*257 + jj + 1] = v.y;
            rows[kk*257 + jj + 2] = v.z;
            rows[kk*257 + jj + 3] = v.w;
        }
        __syncthreads();
        float acc = 0.0f;
        int jbase = jg * 16;
        int a = (m * jbase) & 255;
        #pragma unroll
        for (int jq = 0; jq < 16; ++jq) {
            acc = fmaf(rows[kl*257 + jbase + jq],
                       __cosf((float)a * (2.0f * PI_F / 256.0f)), acc);
            a = (a + m) & 255;
        }
        red[kl*17 + jg] = acc;
        __syncthreads();
        if (tid < 16) {
            float ssum = 0.0f;
            #pragma unroll
            for (int g = 0; g < 16; ++g) ssum += red[tid*17 + g];
            sFre[c*16 + tid] = ssum * (2.0f * PI_F / 256.0f);
        }
    }
    __syncthreads();

    float acc = 0.0f;
    if (tid < 200) {
        int l = tid >> 2, kq = tid & 3;
        #pragma unroll 8
        for (int i = 0; i < 32; ++i)
            acc = fmaf(Wl[l*129 + kq*32 + i], sFre[kq*32 + i], acc);
    }
    __syncthreads();
    red[tid < 200 ? tid : 200] = acc;
    __syncthreads();
    if (tid < LMAX)
        out[(b*LMAX + tid)*MMAX + m] =
            red[4*tid] + red[4*tid+1] + red[4*tid+2] + red[4*tid+3];
}

extern "C" void kernel_launch(void* const* d_in, const int* in_sizes, int n_in,
                              void* d_out, int out_size, void* d_ws, size_t ws_size,
                              hipStream_t stream) {
    const float* target = (const float*)d_in[0];
    float* out = (float*)d_out;
    float* ws  = (float*)d_ws;

    float2* pt_s  = (float2*)ws;                       // 2*2048 float2 = 8192 f
    float*  rho_s = ws + 2*NPTS*2;                     // 4096 f
    int*    bstart = (int*)(ws + 2*NPTS*2 + BATCH*NPTS); // 130 ints (pad to 256)
    float*  f     = ws + 2*NPTS*2 + BATCH*NPTS + 256;  // B*MGRID = 65536 f

    k_sort<<<BATCH, 256, 0, stream>>>(target, pt_s, rho_s, bstart);
    k_nn<<<BATCH*NLON, 512, 0, stream>>>(pt_s, rho_s, bstart, f);
    k_fftsht<<<BATCH*MMAX, 256, 0, stream>>>(f, out);
}

// Round 6
// 85.771 us; speedup vs baseline: 1.2573x; 1.1037x over previous
//
#include <hip/hip_runtime.h>
#include <math.h>
#include <stdint.h>

#define NLAT 128
#define NLON 256
#define LMAX 50
#define MMAX 50
#define MGRID (NLAT*NLON)   // 32768
#define BATCH 2
#define NPTS 2048
#define NBKT 64
#define PI_F 3.14159265358979323846f

typedef float v2f __attribute__((ext_vector_type(2)));

__device__ __forceinline__ uint32_t umin32(uint32_t a, uint32_t b) { return a < b ? a : b; }
__device__ __forceinline__ uint32_t umax32(uint32_t a, uint32_t b) { return a > b ? a : b; }

// ============ kernel 1: fused cart->sph + theta counting-sort + windowed
// 3-NN + weighted combine -> f.  One block per (b, lon j): gy uniform.
// 8 waves: (lat half) x (4 candidate partitions); LDS top-3 key merge.
__global__ __launch_bounds__(512, 2)
void k_nn(const float* __restrict__ target, float* __restrict__ f) {
    __shared__ float2   s_all[NPTS];                 // theta-sorted (phi, py)
    __shared__ float    s_rall[NPTS];
    __shared__ __attribute__((aligned(16))) float2 s_pt[2056];  // window+sentinel
    __shared__ float    s_rho[2056];
    __shared__ uint32_t s_keys[8][64][3];
    __shared__ int      cnt[NBKT], start[NBKT + 1], cur[NBKT];
    int b = blockIdx.x >> 8;
    int j = blockIdx.x & 255;
    int tid = threadIdx.x;
    const float* tg = target + b * NPTS * 3;

    // ---- phase 1: cart->sph (4 pts/thread) + bucket count
    if (tid < NBKT) cnt[tid] = 0;
    __syncthreads();
    float ph[4], py[4], rh[4]; int bk[4];
    #pragma unroll
    for (int c = 0; c < 4; ++c) {
        int p = tid + c * 512;
        float x = tg[p*3], y = tg[p*3+1], z = tg[p*3+2];
        float r = sqrtf(fmaf(x, x, fmaf(y, y, z*z)));
        float cc = fminf(1.f, fmaxf(-1.f, z / r));
        float pyv = acosf(cc) - PI_F;                // [-pi, 0]
        ph[c] = atan2f(y, x); py[c] = pyv; rh[c] = r;
        int bb = (int)floorf((pyv + PI_F) * ((float)NBKT / PI_F));
        bk[c] = min(NBKT-1, max(0, bb));
        atomicAdd(&cnt[bk[c]], 1);
    }
    __syncthreads();
    if (tid == 0) {
        int s = 0;
        for (int i = 0; i < NBKT; ++i) { start[i] = s; cur[i] = s; s += cnt[i]; }
        start[NBKT] = s;
    }
    __syncthreads();
    #pragma unroll
    for (int c = 0; c < 4; ++c) {
        int pos = atomicAdd(&cur[bk[c]], 1);
        s_all[pos]  = make_float2(ph[c], py[c]);
        s_rall[pos] = rh[c];
    }
    __syncthreads();

    // ---- phase 2: block-uniform candidate window [lo, hi] buckets
    float gy = (float)(j - 128) * (PI_F / 128.0f);
    int c0 = (int)floorf((gy + PI_F) * ((float)NBKT / PI_F));
    c0 = min(NBKT-1, max(0, c0));
    int lo = max(0, c0 - 8), hi = min(NBKT-1, c0 + 8);
    int cw = start[hi+1] - start[lo];
    while (cw < 256 && (lo > 0 || hi < NBKT-1)) {
        if (lo > 0) --lo;
        if (hi < NBKT-1) ++hi;
        cw = start[hi+1] - start[lo];
    }
    int off = start[lo];
    for (int i = tid; i < cw; i += 512) {
        s_pt[i]  = s_all[off + i];
        s_rho[i] = s_rall[off + i];
    }
    int q = ((cw + 3) / 4 + 1) & ~1;                 // even, 4q >= cw, <= 2052
    for (int i = cw + tid; i < 4*q; i += 512) {
        s_pt[i] = make_float2(1e15f, 1e15f);         // sentinel never wins
        s_rho[i] = 0.f;
    }
    __syncthreads();

    // ---- phase 3: per-wave top-3 over its candidate partition
    int lane = tid & 63;
    int wv   = tid >> 6;                             // 0..7
    int part = wv & 3;
    int lat  = lane + ((wv >> 2) << 6);
    float gx = (float)lat * (PI_F / 128.0f);
    v2f gx2 = {gx, gx}, gy2 = {gy, gy};
    uint32_t k0 = ~0u, k1 = ~0u, k2 = ~0u;
    uint32_t nb = (uint32_t)(part * q);
    const float4* p4 = (const float4*)(s_pt + part * q);
    int iters = q >> 1;
    #pragma unroll 4
    for (int i = 0; i < iters; ++i) {
        float4 Q = p4[i];                            // wave-uniform b128 broadcast
        v2f px = {Q.x, Q.z}, pyy = {Q.y, Q.w};
        v2f dp = gx2 - px, dt = gy2 - pyy;
        v2f d = dp * dp;
        d = dt * dt + d;
        uint32_t key0 = (__float_as_uint(d.x) & 0xFFFFF800u) | (nb + 2u*i);
        uint32_t key1 = (__float_as_uint(d.y) & 0xFFFFF800u) | (nb + 2u*i + 1u);
        uint32_t t1;
        t1 = umin32(umax32(key0, k0), k1);
        k2 = umin32(umax32(key0, k1), k2);
        k0 = umin32(key0, k0); k1 = t1;
        t1 = umin32(umax32(key1, k0), k1);
        k2 = umin32(umax32(key1, k1), k2);
        k0 = umin32(key1, k0); k1 = t1;
    }
    s_keys[wv][lane][0] = k0;
    s_keys[wv][lane][1] = k1;
    s_keys[wv][lane][2] = k2;
    __syncthreads();

    // ---- phase 4: merge 4 partitions, weighted combine, write column
    if (tid < 128) {
        int lane2 = tid & 63;
        int half  = tid >> 6;
        uint32_t m0 = ~0u, m1 = ~0u, m2 = ~0u;
        #pragma unroll
        for (int w = half*4; w < half*4 + 4; ++w) {
            #pragma unroll
            for (int s = 0; s < 3; ++s) {
                uint32_t key = s_keys[w][lane2][s];
                uint32_t t1 = umin32(umax32(key, m0), m1);
                m2 = umin32(umax32(key, m1), m2);
                m0 = umin32(key, m0); m1 = t1;
            }
        }
        int i0 = m0 & 2047, i1 = m1 & 2047, i2 = m2 & 2047;
        int lat2 = lane2 + (half << 6);
        float gxs = (float)lat2 * (PI_F / 128.0f);
        float2 p0 = s_pt[i0], p1 = s_pt[i1], p2 = s_pt[i2];
        float e, r0, r1, r2;
        e = gxs - p0.x; r0 = e*e; e = gy - p0.y; r0 = sqrtf(fmaf(e, e, r0));
        e = gxs - p1.x; r1 = e*e; e = gy - p1.y; r1 = sqrtf(fmaf(e, e, r1));
        e = gxs - p2.x; r2 = e*e; e = gy - p2.y; r2 = sqrtf(fmaf(e, e, r2));
        float sum = r0 + r1 + r2;
        float interp = (s_rho[i0]*r0 + s_rho[i1]*r1 + s_rho[i2]*r2) / sum;
        f[b * MGRID + lat2 * NLON + j] = interp;
    }
}

// ============ kernel 2: fused W-gen + truncated-DFT + Legendre contraction
// One block per (b,m), 1024 threads (16 waves). No f staging: each f element
// is used once per block -> read float4 straight from L2, wave-shuffle
// reduce per row. W-gen on waves 0-1 overlaps the DFT (no early barrier).
__global__ __launch_bounds__(1024)
void k_fftsht(const float* __restrict__ f, float* __restrict__ out) {
    __shared__ float Wl[LMAX*129];                   // 25.8 KB
    __shared__ float sFre[NLAT];
    __shared__ float red[256];
    int b = blockIdx.x / MMAX;
    int m = blockIdx.x % MMAX;
    int tid = threadIdx.x;

    // ---- phase A (waves 0-1): W[m][l][k] * cc_weight(k) -> Wl[l*129+k]
    if (tid < NLAT) {
        int k = tid;
        float theta = (PI_F * (float)k) / 127.0f;
        float x = __cosf(theta), s = __sinf(theta);
        float S = 0.0f;
        for (int kk = 1; kk <= 63; ++kk)
            S += 2.0f / (4.0f*kk*kk - 1.0f) * __cosf(2.0f * theta * (float)kk);
        float w = (2.0f/127.0f) * (1.0f - S);
        if (k == 0 || k == NLAT-1) w *= 0.5f;
        float pmm = sqrtf(1.0f / (4.0f * PI_F));
        for (int i = 1; i <= m; ++i)
            pmm = -sqrtf((2.0f*i + 1.0f) / (2.0f*i)) * s * pmm;
        for (int l = 0; l < m; ++l) Wl[l*129 + k] = 0.0f;
        float Plm2 = pmm;
        Wl[m*129 + k] = Plm2 * w;
        if (m + 1 < LMAX) {
            float Plm1 = sqrtf(2.0f*m + 3.0f) * x * pmm;
            Wl[(m+1)*129 + k] = Plm1 * w;
            for (int l = m + 2; l < LMAX; ++l) {
                float fl = (float)l, fm2 = (float)(m*m);
                float a  = sqrtf((4.0f*fl*fl - 1.0f) / (fl*fl - fm2));
                float bb = sqrtf(((fl-1.0f)*(fl-1.0f) - fm2) /
                                 (4.0f*(fl-1.0f)*(fl-1.0f) - 1.0f));
                float P = a * (x * Plm1 - bb * Plm2);
                Wl[l*129 + k] = P * w;
                Plm2 = Plm1; Plm1 = P;
            }
        }
    }

    // ---- phase B: DFT. wave w owns rows k = 8w..8w+7; lane reads float4.
    {
        int wv = tid >> 6, lane = tid & 63;
        const float4* fb4 = (const float4*)(f + b * MGRID);
        #pragma unroll
        for (int r = 0; r < 8; ++r) {
            int k = wv * 8 + r;
            float4 v = fb4[k * 64 + lane];           // coalesced, L2-resident
            int a = (m * 4 * lane) & 255;            // (m*j) mod 256
            float p;
            p  = v.x * __cosf((float)a * (2.0f * PI_F / 256.0f)); a = (a + m) & 255;
            p  = fmaf(v.y, __cosf((float)a * (2.0f * PI_F / 256.0f)), p); a = (a + m) & 255;
            p  = fmaf(v.z, __cosf((float)a * (2.0f * PI_F / 256.0f)), p); a = (a + m) & 255;
            p  = fmaf(v.w, __cosf((float)a * (2.0f * PI_F / 256.0f)), p);
            #pragma unroll
            for (int sh = 1; sh < 64; sh <<= 1)
                p += __shfl_xor(p, sh);
            if (lane == 0) sFre[k] = p * (2.0f * PI_F / 256.0f);
        }
    }
    __syncthreads();

    // ---- phase C: out[b,l,m] = sum_k Wl[l][k] * sFre[k]
    float acc = 0.0f;
    if (tid < 200) {
        int l = tid >> 2, kq = tid & 3;
        #pragma unroll 8
        for (int i = 0; i < 32; ++i)
            acc = fmaf(Wl[l*129 + kq*32 + i], sFre[kq*32 + i], acc);
    }
    if (tid < 256) red[tid] = acc;                   // 200..255 write 0
    __syncthreads();
    if (tid < LMAX)
        out[(b*LMAX + tid)*MMAX + m] =
            red[4*tid] + red[4*tid+1] + red[4*tid+2] + red[4*tid+3];
}

extern "C" void kernel_launch(void* const* d_in, const int* in_sizes, int n_in,
                              void* d_out, int out_size, void* d_ws, size_t ws_size,
                              hipStream_t stream) {
    const float* target = (const float*)d_in[0];
    float* out = (float*)d_out;
    float* f   = (float*)d_ws;                       // B*MGRID floats = 256 KB

    k_nn<<<BATCH*NLON, 512, 0, stream>>>(target, f);
    k_fftsht<<<BATCH*MMAX, 1024, 0, stream>>>(f, out);
}

// Round 7
// 79.255 us; speedup vs baseline: 1.3606x; 1.0822x over previous
//
#include <hip/hip_runtime.h>
#include <math.h>
#include <stdint.h>

#define NLAT 128
#define NLON 256
#define LMAX 50
#define MMAX 50
#define MGRID (NLAT*NLON)   // 32768
#define BATCH 2
#define NPTS 2048
#define NBKT 64
#define PI_F 3.14159265358979323846f

typedef float v2f __attribute__((ext_vector_type(2)));

__device__ __forceinline__ uint32_t umin32(uint32_t a, uint32_t b) { return a < b ? a : b; }
__device__ __forceinline__ uint32_t umax32(uint32_t a, uint32_t b) { return a > b ? a : b; }

// ============ kernel 1: fused cart->sph + theta counting-sort + windowed
// 3-NN + weighted combine -> f.  One block per (b, lon j): gy uniform.
// 8 waves: (lat half) x (4 candidate partitions); LDS top-3 key merge.
__global__ __launch_bounds__(512, 2)
void k_nn(const float* __restrict__ target, float* __restrict__ f) {
    __shared__ float2   s_all[NPTS];                 // theta-sorted (phi, py)
    __shared__ float    s_rall[NPTS];
    __shared__ __attribute__((aligned(16))) float2 s_pt[2056];  // window+sentinel
    __shared__ float    s_rho[2056];
    __shared__ uint32_t s_keys[8][64][3];
    __shared__ int      cnt[NBKT], start[NBKT + 1], cur[NBKT];
    int b = blockIdx.x >> 8;
    int j = blockIdx.x & 255;
    int tid = threadIdx.x;
    const float* tg = target + b * NPTS * 3;

    // ---- phase 1: cart->sph (4 pts/thread) + bucket count
    if (tid < NBKT) cnt[tid] = 0;
    __syncthreads();
    float ph[4], py[4], rh[4]; int bk[4];
    #pragma unroll
    for (int c = 0; c < 4; ++c) {
        int p = tid + c * 512;
        float x = tg[p*3], y = tg[p*3+1], z = tg[p*3+2];
        float r = sqrtf(fmaf(x, x, fmaf(y, y, z*z)));
        float cc = fminf(1.f, fmaxf(-1.f, z / r));
        float pyv = acosf(cc) - PI_F;                // [-pi, 0]
        ph[c] = atan2f(y, x); py[c] = pyv; rh[c] = r;
        int bb = (int)floorf((pyv + PI_F) * ((float)NBKT / PI_F));
        bk[c] = min(NBKT-1, max(0, bb));
        atomicAdd(&cnt[bk[c]], 1);
    }
    __syncthreads();
    if (tid == 0) {
        int s = 0;
        for (int i = 0; i < NBKT; ++i) { start[i] = s; cur[i] = s; s += cnt[i]; }
        start[NBKT] = s;
    }
    __syncthreads();
    #pragma unroll
    for (int c = 0; c < 4; ++c) {
        int pos = atomicAdd(&cur[bk[c]], 1);
        s_all[pos]  = make_float2(ph[c], py[c]);
        s_rall[pos] = rh[c];
    }
    __syncthreads();

    // ---- phase 2: block-uniform candidate window [lo, hi] buckets
    float gy = (float)(j - 128) * (PI_F / 128.0f);
    int c0 = (int)floorf((gy + PI_F) * ((float)NBKT / PI_F));
    c0 = min(NBKT-1, max(0, c0));
    int lo = max(0, c0 - 5), hi = min(NBKT-1, c0 + 5);
    int cw = start[hi+1] - start[lo];
    while (cw < 192 && (lo > 0 || hi < NBKT-1)) {
        if (lo > 0) --lo;
        if (hi < NBKT-1) ++hi;
        cw = start[hi+1] - start[lo];
    }
    int off = start[lo];
    for (int i = tid; i < cw; i += 512) {
        s_pt[i]  = s_all[off + i];
        s_rho[i] = s_rall[off + i];
    }
    int q = ((cw + 3) / 4 + 1) & ~1;                 // even, 4q >= cw, idx <= 2047
    for (int i = cw + tid; i < 4*q; i += 512) {
        s_pt[i] = make_float2(1e15f, 1e15f);         // sentinel never wins
        s_rho[i] = 0.f;
    }
    __syncthreads();

    // ---- phase 3: per-wave top-3 over its candidate partition
    int lane = tid & 63;
    int wv   = tid >> 6;                             // 0..7
    int part = wv & 3;
    int lat  = lane + ((wv >> 2) << 6);
    float gx = (float)lat * (PI_F / 128.0f);
    v2f gx2 = {gx, gx}, gy2 = {gy, gy};
    uint32_t k0 = ~0u, k1 = ~0u, k2 = ~0u;
    uint32_t nb = (uint32_t)(part * q);
    const float4* p4 = (const float4*)(s_pt + part * q);
    int iters = q >> 1;
    #pragma unroll 4
    for (int i = 0; i < iters; ++i) {
        float4 Q = p4[i];                            // wave-uniform b128 broadcast
        v2f px = {Q.x, Q.z}, pyy = {Q.y, Q.w};
        v2f dp = gx2 - px, dt = gy2 - pyy;
        v2f d = dp * dp;
        d = dt * dt + d;
        uint32_t key0 = (__float_as_uint(d.x) & 0xFFFFF800u) | (nb + 2u*i);
        uint32_t key1 = (__float_as_uint(d.y) & 0xFFFFF800u) | (nb + 2u*i + 1u);
        uint32_t t1;
        t1 = umin32(umax32(key0, k0), k1);
        k2 = umin32(umax32(key0, k1), k2);
        k0 = umin32(key0, k0); k1 = t1;
        t1 = umin32(umax32(key1, k0), k1);
        k2 = umin32(umax32(key1, k1), k2);
        k0 = umin32(key1, k0); k1 = t1;
    }
    s_keys[wv][lane][0] = k0;
    s_keys[wv][lane][1] = k1;
    s_keys[wv][lane][2] = k2;
    __syncthreads();

    // ---- phase 4: merge 4 partitions, weighted combine, write column
    if (tid < 128) {
        int lane2 = tid & 63;
        int half  = tid >> 6;
        uint32_t m0 = ~0u, m1 = ~0u, m2 = ~0u;
        #pragma unroll
        for (int w = half*4; w < half*4 + 4; ++w) {
            #pragma unroll
            for (int s = 0; s < 3; ++s) {
                uint32_t key = s_keys[w][lane2][s];
                uint32_t t1 = umin32(umax32(key, m0), m1);
                m2 = umin32(umax32(key, m1), m2);
                m0 = umin32(key, m0); m1 = t1;
            }
        }
        int i0 = m0 & 2047, i1 = m1 & 2047, i2 = m2 & 2047;
        int lat2 = lane2 + (half << 6);
        float gxs = (float)lat2 * (PI_F / 128.0f);
        float2 p0 = s_pt[i0], p1 = s_pt[i1], p2 = s_pt[i2];
        float e, r0, r1, r2;
        e = gxs - p0.x; r0 = e*e; e = gy - p0.y; r0 = sqrtf(fmaf(e, e, r0));
        e = gxs - p1.x; r1 = e*e; e = gy - p1.y; r1 = sqrtf(fmaf(e, e, r1));
        e = gxs - p2.x; r2 = e*e; e = gy - p2.y; r2 = sqrtf(fmaf(e, e, r2));
        float sum = r0 + r1 + r2;
        float interp = (s_rho[i0]*r0 + s_rho[i1]*r1 + s_rho[i2]*r2) / sum;
        f[b * MGRID + lat2 * NLON + j] = interp;
    }
}

// ============ kernel 2: fused W-gen + truncated-DFT + Legendre contraction
// One block per (b,m), 1024 threads. Phase B: thread = (row k, eighth g);
// 8 contiguous float4 reads + 32 fma/cos, NO cross-lane ops; LDS partial
// reduce (pitch 9). W-gen on waves 0-1 overlaps other waves' phase B.
__global__ __launch_bounds__(1024)
void k_fftsht(const float* __restrict__ f, float* __restrict__ out) {
    __shared__ float Wl[LMAX*129];                   // 25.8 KB
    __shared__ float red[NLAT*9];                    // 4.6 KB, pitch 9
    __shared__ float sFre[NLAT];
    __shared__ float cred[256];
    int b = blockIdx.x / MMAX;
    int m = blockIdx.x % MMAX;
    int tid = threadIdx.x;

    // ---- phase A (waves 0-1): W[m][l][k] * cc_weight(k) -> Wl[l*129+k]
    if (tid < NLAT) {
        int k = tid;
        float theta = (PI_F * (float)k) / 127.0f;
        float x = __cosf(theta), s = __sinf(theta);
        float S = 0.0f;
        for (int kk = 1; kk <= 63; ++kk)
            S += 2.0f / (4.0f*kk*kk - 1.0f) * __cosf(2.0f * theta * (float)kk);
        float w = (2.0f/127.0f) * (1.0f - S);
        if (k == 0 || k == NLAT-1) w *= 0.5f;
        float pmm = sqrtf(1.0f / (4.0f * PI_F));
        for (int i = 1; i <= m; ++i)
            pmm = -sqrtf((2.0f*i + 1.0f) / (2.0f*i)) * s * pmm;
        for (int l = 0; l < m; ++l) Wl[l*129 + k] = 0.0f;
        float Plm2 = pmm;
        Wl[m*129 + k] = Plm2 * w;
        if (m + 1 < LMAX) {
            float Plm1 = sqrtf(2.0f*m + 3.0f) * x * pmm;
            Wl[(m+1)*129 + k] = Plm1 * w;
            for (int l = m + 2; l < LMAX; ++l) {
                float fl = (float)l, fm2 = (float)(m*m);
                float a  = sqrtf((4.0f*fl*fl - 1.0f) / (fl*fl - fm2));
                float bb = sqrtf(((fl-1.0f)*(fl-1.0f) - fm2) /
                                 (4.0f*(fl-1.0f)*(fl-1.0f) - 1.0f));
                float P = a * (x * Plm1 - bb * Plm2);
                Wl[l*129 + k] = P * w;
                Plm2 = Plm1; Plm1 = P;
            }
        }
    }

    // ---- phase B: partial DFT. k = tid>>3 (row), g = tid&7 (eighth).
    {
        int k = tid >> 3, g = tid & 7;
        const float4* fb4 = (const float4*)(f + b * MGRID);
        float p = 0.0f;
        int a = (m * 32 * g) & 255;                  // (m*j) mod 256 at j=32g
        #pragma unroll
        for (int i = 0; i < 8; ++i) {
            float4 v = fb4[k * 64 + g * 8 + i];      // j = 32g + 4i
            p = fmaf(v.x, __cosf((float)a * (2.0f*PI_F/256.0f)), p); a = (a + m) & 255;
            p = fmaf(v.y, __cosf((float)a * (2.0f*PI_F/256.0f)), p); a = (a + m) & 255;
            p = fmaf(v.z, __cosf((float)a * (2.0f*PI_F/256.0f)), p); a = (a + m) & 255;
            p = fmaf(v.w, __cosf((float)a * (2.0f*PI_F/256.0f)), p); a = (a + m) & 255;
        }
        red[k * 9 + g] = p;
    }
    __syncthreads();
    if (tid < NLAT) {
        float s = 0.0f;
        #pragma unroll
        for (int g = 0; g < 8; ++g) s += red[tid * 9 + g];
        sFre[tid] = s * (2.0f * PI_F / 256.0f);
    }
    __syncthreads();

    // ---- phase C: out[b,l,m] = sum_k Wl[l][k] * sFre[k]
    float acc = 0.0f;
    if (tid < 200) {
        int l = tid >> 2, kq = tid & 3;
        #pragma unroll 8
        for (int i = 0; i < 32; ++i)
            acc = fmaf(Wl[l*129 + kq*32 + i], sFre[kq*32 + i], acc);
    }
    if (tid < 256) cred[tid] = acc;                  // 200..255 write 0
    __syncthreads();
    if (tid < LMAX)
        out[(b*LMAX + tid)*MMAX + m] =
            cred[4*tid] + cred[4*tid+1] + cred[4*tid+2] + cred[4*tid+3];
}

extern "C" void kernel_launch(void* const* d_in, const int* in_sizes, int n_in,
                              void* d_out, int out_size, void* d_ws, size_t ws_size,
                              hipStream_t stream) {
    const float* target = (const float*)d_in[0];
    float* out = (float*)d_out;
    float* f   = (float*)d_ws;                       // B*MGRID floats = 256 KB

    k_nn<<<BATCH*NLON, 512, 0, stream>>>(target, f);
    k_fftsht<<<BATCH*MMAX, 1024, 0, stream>>>(f, out);
}

// Round 8
// 75.411 us; speedup vs baseline: 1.4300x; 1.0510x over previous
//
#include <hip/hip_runtime.h>
#include <math.h>
#include <stdint.h>

#define NLAT 128
#define NLON 256
#define LMAX 50
#define MMAX 50
#define MGRID (NLAT*NLON)   // 32768
#define BATCH 2
#define NPTS 2048
#define NBKT 64
#define PI_F 3.14159265358979323846f

typedef float v2f __attribute__((ext_vector_type(2)));

__device__ __forceinline__ uint32_t umin32(uint32_t a, uint32_t b) { return a < b ? a : b; }
__device__ __forceinline__ uint32_t umax32(uint32_t a, uint32_t b) { return a > b ? a : b; }

// ============ kernel 1: fused cart->sph + theta counting-sort + windowed
// 3-NN + weighted combine -> f.  One block per (b, lon j): gy uniform.
// 8 waves: (lat half) x (4 candidate partitions); LDS top-3 key merge.
__global__ __launch_bounds__(512, 2)
void k_nn(const float* __restrict__ target, float* __restrict__ f) {
    __shared__ float2   s_all[NPTS];                 // theta-sorted (phi, py)
    __shared__ float    s_rall[NPTS];
    __shared__ __attribute__((aligned(16))) float2 s_pt[2056];  // window+sentinel
    __shared__ float    s_rho[2056];
    __shared__ uint32_t s_keys[8][64][3];
    __shared__ int      cnt[NBKT], start[NBKT + 1], cur[NBKT];
    __shared__ int      s_win[2];
    int b = blockIdx.x >> 8;
    int j = blockIdx.x & 255;
    int tid = threadIdx.x;
    const float* tg = target + b * NPTS * 3;

    // ---- phase 1: cart->sph (4 pts/thread) + bucket count
    if (tid < NBKT) cnt[tid] = 0;
    __syncthreads();
    float ph[4], py[4], rh[4]; int bk[4];
    #pragma unroll
    for (int c = 0; c < 4; ++c) {
        int p = tid + c * 512;
        float x = tg[p*3], y = tg[p*3+1], z = tg[p*3+2];
        float r = sqrtf(fmaf(x, x, fmaf(y, y, z*z)));
        float cc = fminf(1.f, fmaxf(-1.f, z / r));
        float pyv = acosf(cc) - PI_F;                // [-pi, 0]
        ph[c] = atan2f(y, x); py[c] = pyv; rh[c] = r;
        int bb = (int)floorf((pyv + PI_F) * ((float)NBKT / PI_F));
        bk[c] = min(NBKT-1, max(0, bb));
        atomicAdd(&cnt[bk[c]], 1);
    }
    __syncthreads();
    if (tid == 0) {
        int s = 0;
        for (int i = 0; i < NBKT; ++i) { start[i] = s; cur[i] = s; s += cnt[i]; }
        start[NBKT] = s;
    }
    __syncthreads();
    #pragma unroll
    for (int c = 0; c < 4; ++c) {
        int pos = atomicAdd(&cur[bk[c]], 1);
        s_all[pos]  = make_float2(ph[c], py[c]);
        s_rall[pos] = rh[c];
    }

    // ---- phase 2: block-uniform candidate window, parallel radius search.
    // Serial expansion after n steps == clamped radius n, so lane t tests
    // radius t and ballot finds the first admissible radius. Wave 0 only.
    float gy = (float)(j - 128) * (PI_F / 128.0f);
    int c0 = (int)floorf((gy + PI_F) * ((float)NBKT / PI_F));
    c0 = min(NBKT-1, max(0, c0));
    __syncthreads();                                 // start[] ready
    if (tid < 64) {
        int t = tid;
        int lo_t = max(0, c0 - 5 - t), hi_t = min(NBKT-1, c0 + 5 + t);
        int cw_t = start[hi_t+1] - start[lo_t];
        unsigned long long ok =
            __ballot(cw_t >= 192 || (lo_t == 0 && hi_t == NBKT-1));
        int t0 = __ffsll((unsigned long long)ok) - 1;
        if (tid == 0) {
            s_win[0] = max(0, c0 - 5 - t0);
            s_win[1] = min(NBKT-1, c0 + 5 + t0);
        }
    }
    __syncthreads();
    int lo = s_win[0], hi = s_win[1];
    int cw = start[hi+1] - start[lo];
    int off = start[lo];
    for (int i = tid; i < cw; i += 512) {
        s_pt[i]  = s_all[off + i];
        s_rho[i] = s_rall[off + i];
    }
    int q = ((cw + 3) / 4 + 1) & ~1;                 // even, 4q >= cw, idx <= 2047
    for (int i = cw + tid; i < 4*q; i += 512) {
        s_pt[i] = make_float2(1e15f, 1e15f);         // sentinel never wins
        s_rho[i] = 0.f;
    }
    __syncthreads();

    // ---- phase 3: per-wave top-3 over its candidate partition
    int lane = tid & 63;
    int wv   = tid >> 6;                             // 0..7
    int part = wv & 3;
    int lat  = lane + ((wv >> 2) << 6);
    float gx = (float)lat * (PI_F / 128.0f);
    v2f gx2 = {gx, gx}, gy2 = {gy, gy};
    uint32_t k0 = ~0u, k1 = ~0u, k2 = ~0u;
    uint32_t nb = (uint32_t)(part * q);
    const float4* p4 = (const float4*)(s_pt + part * q);
    int iters = q >> 1;
    #pragma unroll 4
    for (int i = 0; i < iters; ++i) {
        float4 Q = p4[i];                            // wave-uniform b128 broadcast
        v2f px = {Q.x, Q.z}, pyy = {Q.y, Q.w};
        v2f dp = gx2 - px, dt = gy2 - pyy;
        v2f d = dp * dp;
        d = dt * dt + d;
        uint32_t key0 = (__float_as_uint(d.x) & 0xFFFFF800u) | (nb + 2u*i);
        uint32_t key1 = (__float_as_uint(d.y) & 0xFFFFF800u) | (nb + 2u*i + 1u);
        uint32_t t1;
        t1 = umin32(umax32(key0, k0), k1);
        k2 = umin32(umax32(key0, k1), k2);
        k0 = umin32(key0, k0); k1 = t1;
        t1 = umin32(umax32(key1, k0), k1);
        k2 = umin32(umax32(key1, k1), k2);
        k0 = umin32(key1, k0); k1 = t1;
    }
    s_keys[wv][lane][0] = k0;
    s_keys[wv][lane][1] = k1;
    s_keys[wv][lane][2] = k2;
    __syncthreads();

    // ---- phase 4: merge 4 partitions, weighted combine, write column
    if (tid < 128) {
        int lane2 = tid & 63;
        int half  = tid >> 6;
        uint32_t m0 = ~0u, m1 = ~0u, m2 = ~0u;
        #pragma unroll
        for (int w = half*4; w < half*4 + 4; ++w) {
            #pragma unroll
            for (int s = 0; s < 3; ++s) {
                uint32_t key = s_keys[w][lane2][s];
                uint32_t t1 = umin32(umax32(key, m0), m1);
                m2 = umin32(umax32(key, m1), m2);
                m0 = umin32(key, m0); m1 = t1;
            }
        }
        int i0 = m0 & 2047, i1 = m1 & 2047, i2 = m2 & 2047;
        int lat2 = lane2 + (half << 6);
        float gxs = (float)lat2 * (PI_F / 128.0f);
        float2 p0 = s_pt[i0], p1 = s_pt[i1], p2 = s_pt[i2];
        float e, r0, r1, r2;
        e = gxs - p0.x; r0 = e*e; e = gy - p0.y; r0 = sqrtf(fmaf(e, e, r0));
        e = gxs - p1.x; r1 = e*e; e = gy - p1.y; r1 = sqrtf(fmaf(e, e, r1));
        e = gxs - p2.x; r2 = e*e; e = gy - p2.y; r2 = sqrtf(fmaf(e, e, r2));
        float sum = r0 + r1 + r2;
        float interp = (s_rho[i0]*r0 + s_rho[i1]*r1 + s_rho[i2]*r2) / sum;
        f[b * MGRID + lat2 * NLON + j] = interp;
    }
}

// ============ kernel 2: fused W-gen + truncated-DFT + Legendre contraction
// One block per (b,m), 1024 threads. Waves 8-11 precompute recurrence coeffs
// a[l],bb[l], C(m) (log-prefix product), CC weights w(k) CONCURRENTLY with
// phase B's partial DFT; threads 0-127 then build Wl at 3 ops per l.
__global__ __launch_bounds__(1024)
void k_fftsht(const float* __restrict__ f, float* __restrict__ out) {
    __shared__ float Wl[LMAX*129];                   // 25.8 KB
    __shared__ float red[NLAT*9];                    // 4.6 KB, pitch 9
    __shared__ float sFre[NLAT];
    __shared__ float cred[256];
    __shared__ float s_a[LMAX], s_bb[LMAX], s_w[NLAT];
    __shared__ float s_cm;
    int b = blockIdx.x / MMAX;
    int m = blockIdx.x % MMAX;
    int tid = threadIdx.x;

    // ---- concurrent precompute (no barrier needed before phase B)
    if (tid >= 512 && tid < 576) {                   // wave 8: a[l], bb[l]
        int l = tid - 512;
        if (l < LMAX) {
            float fl = (float)l, fm2 = (float)(m*m);
            s_a[l]  = sqrtf((4.f*fl*fl - 1.f) / fmaxf(fl*fl - fm2, 0.25f));
            float flm1 = fl - 1.f;
            s_bb[l] = sqrtf(fmaxf(flm1*flm1 - fm2, 0.f) /
                            fmaxf(4.f*flm1*flm1 - 1.f, 0.25f));
        }
    } else if (tid >= 576 && tid < 640) {            // wave 9: C(m) log-prefix
        int i = tid - 576;
        float v = (i >= 1 && i <= m)
                  ? 0.5f * __log2f((2.f*i + 1.f) / (2.f*i)) : 0.f;
        #pragma unroll
        for (int sh = 1; sh < 64; sh <<= 1) v += __shfl_xor(v, sh);
        if (i == 0) s_cm = ((m & 1) ? -1.f : 1.f) * exp2f(v);
    } else if (tid >= 640 && tid < 768) {            // waves 10-11: CC w(k)
        int k = tid - 640;
        float theta = (PI_F * (float)k) / 127.0f;
        float S = 0.0f;
        for (int kk = 1; kk <= 63; ++kk)
            S += 2.0f / (4.0f*kk*kk - 1.0f) * __cosf(2.0f * theta * (float)kk);
        float w = (2.0f/127.0f) * (1.0f - S);
        if (k == 0 || k == NLAT-1) w *= 0.5f;
        s_w[k] = w;
    }

    // ---- phase B: partial DFT. k = tid>>3 (row), g = tid&7 (eighth).
    {
        int k = tid >> 3, g = tid & 7;
        const float4* fb4 = (const float4*)(f + b * MGRID);
        float p = 0.0f;
        int a = (m * 32 * g) & 255;                  // (m*j) mod 256 at j=32g
        #pragma unroll
        for (int i = 0; i < 8; ++i) {
            float4 v = fb4[k * 64 + g * 8 + i];      // j = 32g + 4i
            p = fmaf(v.x, __cosf((float)a * (2.0f*PI_F/256.0f)), p); a = (a + m) & 255;
            p = fmaf(v.y, __cosf((float)a * (2.0f*PI_F/256.0f)), p); a = (a + m) & 255;
            p = fmaf(v.z, __cosf((float)a * (2.0f*PI_F/256.0f)), p); a = (a + m) & 255;
            p = fmaf(v.w, __cosf((float)a * (2.0f*PI_F/256.0f)), p); a = (a + m) & 255;
        }
        red[k * 9 + g] = p;
    }
    __syncthreads();

    // ---- phase A': threads 0-127: row-sum -> sFre, then Wl via shared coeffs
    if (tid < NLAT) {
        int k = tid;
        float srow = 0.0f;
        #pragma unroll
        for (int g = 0; g < 8; ++g) srow += red[k * 9 + g];
        sFre[k] = srow * (2.0f * PI_F / 256.0f);

        float theta = (PI_F * (float)k) / 127.0f;
        float x = __cosf(theta), sn = __sinf(theta);
        float w = s_w[k];
        // pmm = C(m) * |sn|^m * sign(sn)^m * sqrt(1/4pi); sn<0 only at k=127
        float pmm;
        if (m == 0) pmm = 0.28209479177f;
        else {
            float mag = exp2f((float)m * __log2f(fabsf(sn)));
            float sg  = (sn < 0.f && (m & 1)) ? -1.f : 1.f;
            pmm = 0.28209479177f * s_cm * mag * sg;
        }
        for (int l = 0; l < m; ++l) Wl[l*129 + k] = 0.0f;
        float Plm2 = pmm;
        Wl[m*129 + k] = Plm2 * w;
        if (m + 1 < LMAX) {
            float Plm1 = sqrtf(2.0f*m + 3.0f) * x * pmm;
            Wl[(m+1)*129 + k] = Plm1 * w;
            for (int l = m + 2; l < LMAX; ++l) {
                float P = s_a[l] * fmaf(-s_bb[l], Plm2, x * Plm1);
                Wl[l*129 + k] = P * w;
                Plm2 = Plm1; Plm1 = P;
            }
        }
    }
    __syncthreads();

    // ---- phase C: out[b,l,m] = sum_k Wl[l][k] * sFre[k]
    float acc = 0.0f;
    if (tid < 200) {
        int l = tid >> 2, kq = tid & 3;
        #pragma unroll 8
        for (int i = 0; i < 32; ++i)
            acc = fmaf(Wl[l*129 + kq*32 + i], sFre[kq*32 + i], acc);
    }
    if (tid < 256) cred[tid] = acc;                  // 200..255 write 0
    __syncthreads();
    if (tid < LMAX)
        out[(b*LMAX + tid)*MMAX + m] =
            cred[4*tid] + cred[4*tid+1] + cred[4*tid+2] + cred[4*tid+3];
}

extern "C" void kernel_launch(void* const* d_in, const int* in_sizes, int n_in,
                              void* d_out, int out_size, void* d_ws, size_t ws_size,
                              hipStream_t stream) {
    const float* target = (const float*)d_in[0];
    float* out = (float*)d_out;
    float* f   = (float*)d_ws;                       // B*MGRID floats = 256 KB

    k_nn<<<BATCH*NLON, 512, 0, stream>>>(target, f);
    k_fftsht<<<BATCH*MMAX, 1024, 0, stream>>>(f, out);
}